// Round 1
// baseline (70.731 us; speedup 1.0000x reference)
//
#include <hip/hip_runtime.h>

#define EMB_DIM 64
#define LANES_PER_ROW 16   // 16 lanes x float4 = 64 floats = one embedding row

__device__ __forceinline__ int lower_bound_i32(const int* __restrict__ arr, int n, int val) {
    int lo = 0, hi = n;
    while (lo < hi) {
        int mid = (lo + hi) >> 1;
        if (arr[mid] < val) lo = mid + 1;
        else hi = mid;
    }
    return lo;
}

__global__ __launch_bounds__(256) void emb_lookup_mean_kernel(
        const int*   __restrict__ values,
        const int*   __restrict__ rows,
        const float* __restrict__ table,
        float*       __restrict__ out,
        int nnz, int n_rows) {
    int tid  = blockIdx.x * blockDim.x + threadIdx.x;
    int row  = tid >> 4;          // 16 lanes per output row
    int lane = tid & 15;
    if (row >= n_rows) return;

    // Segment bounds for this row in the sorted row_indices array.
    int start = lower_bound_i32(rows, nnz, row);
    int end   = lower_bound_i32(rows, nnz, row + 1);

    float4 acc = make_float4(0.f, 0.f, 0.f, 0.f);
    for (int j = start; j < end; ++j) {
        int key = values[j];  // uniform within the 16-lane group -> broadcast
        const float4* p = reinterpret_cast<const float4*>(table + (size_t)key * EMB_DIM) + lane;
        float4 v = *p;        // 16 lanes x 16B = coalesced 256B row read
        acc.x += v.x; acc.y += v.y; acc.z += v.z; acc.w += v.w;
    }

    int   cnt = end - start;
    float inv = (cnt > 0) ? (1.0f / (float)cnt) : 0.0f;
    acc.x *= inv; acc.y *= inv; acc.z *= inv; acc.w *= inv;

    reinterpret_cast<float4*>(out + (size_t)row * EMB_DIM)[lane] = acc;
}

extern "C" void kernel_launch(void* const* d_in, const int* in_sizes, int n_in,
                              void* d_out, int out_size, void* d_ws, size_t ws_size,
                              hipStream_t stream) {
    const int*   values = (const int*)d_in[0];
    const int*   rows   = (const int*)d_in[1];
    const float* table  = (const float*)d_in[2];
    float*       out    = (float*)d_out;

    int nnz    = in_sizes[0];
    int n_rows = out_size / EMB_DIM;   // BATCH * SLOT_NUM = 106496

    int threads_needed = n_rows * LANES_PER_ROW;
    int block = 256;
    int grid  = (threads_needed + block - 1) / block;

    emb_lookup_mean_kernel<<<grid, block, 0, stream>>>(values, rows, table, out,
                                                       nnz, n_rows);
}

// Round 2
// 35.792 us; speedup vs baseline: 1.9762x; 1.9762x over previous
//
#include <hip/hip_runtime.h>

#define EMB_DIM 64
#define LANES_PER_ROW 16   // 16 lanes x float4 = 64 floats = one embedding row

// ---------------- Kernel 1: CSR offsets from sorted row_indices ----------------
__global__ __launch_bounds__(256) void build_offsets_kernel(
        const int* __restrict__ rows,
        int*       __restrict__ off,
        int nnz, int n_rows) {
    int j = blockIdx.x * blockDim.x + threadIdx.x;
    if (j >= nnz) return;
    int r  = rows[j];
    int rp = (j == 0) ? -1 : rows[j - 1];
    // This thread owns all segment starts in (rp, r]
    for (int rr = rp + 1; rr <= r; ++rr) off[rr] = j;
    if (j == nnz - 1) {
        for (int rr = r + 1; rr <= n_rows; ++rr) off[rr] = nnz;
    }
}

// ---------------- Kernel 2: gather + mean using offsets ----------------
__global__ __launch_bounds__(256) void emb_lookup_mean_kernel(
        const int*   __restrict__ values,
        const int*   __restrict__ off,
        const float* __restrict__ table,
        float*       __restrict__ out,
        int n_rows) {
    int tid  = blockIdx.x * blockDim.x + threadIdx.x;
    int row  = tid >> 4;          // 16 lanes per output row
    int lane = tid & 15;
    if (row >= n_rows) return;

    int start = off[row];         // adjacent groups read adjacent ints -> coalesced
    int end   = off[row + 1];
    int cnt   = end - start;

    float4 acc0 = make_float4(0.f, 0.f, 0.f, 0.f);
    float4 acc1 = make_float4(0.f, 0.f, 0.f, 0.f);

    for (int base = start; base < end; base += 16) {
        int m = min(16, end - base);
        // lane-parallel key prefetch: 16 consecutive ints = one 64B coalesced load
        int mykey = (lane < m) ? values[base + lane] : 0;

        int k = 0;
        for (; k + 4 <= m; k += 4) {
            int k0 = __shfl(mykey, k,     16);
            int k1 = __shfl(mykey, k + 1, 16);
            int k2 = __shfl(mykey, k + 2, 16);
            int k3 = __shfl(mykey, k + 3, 16);
            // 4 independent 256B row reads in flight
            float4 v0 = reinterpret_cast<const float4*>(table + (size_t)k0 * EMB_DIM)[lane];
            float4 v1 = reinterpret_cast<const float4*>(table + (size_t)k1 * EMB_DIM)[lane];
            float4 v2 = reinterpret_cast<const float4*>(table + (size_t)k2 * EMB_DIM)[lane];
            float4 v3 = reinterpret_cast<const float4*>(table + (size_t)k3 * EMB_DIM)[lane];
            acc0.x += v0.x; acc0.y += v0.y; acc0.z += v0.z; acc0.w += v0.w;
            acc1.x += v1.x; acc1.y += v1.y; acc1.z += v1.z; acc1.w += v1.w;
            acc0.x += v2.x; acc0.y += v2.y; acc0.z += v2.z; acc0.w += v2.w;
            acc1.x += v3.x; acc1.y += v3.y; acc1.z += v3.z; acc1.w += v3.w;
        }
        for (; k < m; ++k) {
            int key = __shfl(mykey, k, 16);
            float4 v = reinterpret_cast<const float4*>(table + (size_t)key * EMB_DIM)[lane];
            acc0.x += v.x; acc0.y += v.y; acc0.z += v.z; acc0.w += v.w;
        }
    }

    float inv = (cnt > 0) ? (1.0f / (float)cnt) : 0.0f;
    float4 r;
    r.x = (acc0.x + acc1.x) * inv;
    r.y = (acc0.y + acc1.y) * inv;
    r.z = (acc0.z + acc1.z) * inv;
    r.w = (acc0.w + acc1.w) * inv;
    reinterpret_cast<float4*>(out + (size_t)row * EMB_DIM)[lane] = r;
}

// ---------------- Fallback (binary search) if d_ws is too small ----------------
__device__ __forceinline__ int lower_bound_i32(const int* __restrict__ arr, int n, int val) {
    int lo = 0, hi = n;
    while (lo < hi) {
        int mid = (lo + hi) >> 1;
        if (arr[mid] < val) lo = mid + 1;
        else hi = mid;
    }
    return lo;
}

__global__ __launch_bounds__(256) void emb_lookup_mean_bsearch_kernel(
        const int*   __restrict__ values,
        const int*   __restrict__ rows,
        const float* __restrict__ table,
        float*       __restrict__ out,
        int nnz, int n_rows) {
    int tid  = blockIdx.x * blockDim.x + threadIdx.x;
    int row  = tid >> 4;
    int lane = tid & 15;
    if (row >= n_rows) return;
    int start = lower_bound_i32(rows, nnz, row);
    int end   = lower_bound_i32(rows, nnz, row + 1);
    float4 acc = make_float4(0.f, 0.f, 0.f, 0.f);
    for (int j = start; j < end; ++j) {
        int key = values[j];
        float4 v = reinterpret_cast<const float4*>(table + (size_t)key * EMB_DIM)[lane];
        acc.x += v.x; acc.y += v.y; acc.z += v.z; acc.w += v.w;
    }
    int   cnt = end - start;
    float inv = (cnt > 0) ? (1.0f / (float)cnt) : 0.0f;
    acc.x *= inv; acc.y *= inv; acc.z *= inv; acc.w *= inv;
    reinterpret_cast<float4*>(out + (size_t)row * EMB_DIM)[lane] = acc;
}

extern "C" void kernel_launch(void* const* d_in, const int* in_sizes, int n_in,
                              void* d_out, int out_size, void* d_ws, size_t ws_size,
                              hipStream_t stream) {
    const int*   values = (const int*)d_in[0];
    const int*   rows   = (const int*)d_in[1];
    const float* table  = (const float*)d_in[2];
    float*       out    = (float*)d_out;

    int nnz    = in_sizes[0];
    int n_rows = out_size / EMB_DIM;   // BATCH * SLOT_NUM = 106496

    int block = 256;
    int grid2 = (n_rows * LANES_PER_ROW + block - 1) / block;

    size_t off_bytes = (size_t)(n_rows + 1) * sizeof(int);
    if (ws_size >= off_bytes) {
        int* off = (int*)d_ws;
        int grid1 = (nnz + block - 1) / block;
        build_offsets_kernel<<<grid1, block, 0, stream>>>(rows, off, nnz, n_rows);
        emb_lookup_mean_kernel<<<grid2, block, 0, stream>>>(values, off, table, out, n_rows);
    } else {
        emb_lookup_mean_bsearch_kernel<<<grid2, block, 0, stream>>>(values, rows, table, out,
                                                                    nnz, n_rows);
    }
}